// Round 1
// baseline (892.812 us; speedup 1.0000x reference)
//
#include <hip/hip_runtime.h>
#include <hip/hip_bf16.h>

#define NEG_SLOPE 0.2f

static constexpr int NB  = 64;    // batch
static constexpr int SEQ = 1024;  // sequence length (IN_F)
static constexpr int DIMD = 256;  // feature dim

__device__ __forceinline__ float bf2f(unsigned short u) {
    return __uint_as_float(((unsigned int)u) << 16);
}

__device__ __forceinline__ float leaky(float v) {
    return v >= 0.0f ? v : NEG_SLOPE * v;
}

// =====================================================================
// K1: QKV projection (cold path; only runs when gamma != 0)
//   qkv[m, e] = sum_k x[m,k] * qkv_w[e,k] + qkv_b[e]   (stored bf16)
//   M = 64*1024 (flattened b,n), N = 768, K = 256.  NT gemm.
// =====================================================================
__global__ __launch_bounds__(256)
void qkv_gemm(const float* __restrict__ x, const float* __restrict__ w,
              const float* __restrict__ bias, const float* __restrict__ gamma,
              __hip_bfloat16* __restrict__ qkv)
{
    if (gamma[0] == 0.0f) return;   // attention contributes gamma*O only
    __shared__ float As[16][68];
    __shared__ float Bs[16][68];
    const int m0 = blockIdx.y * 64;
    const int n0 = blockIdx.x * 64;
    const int t  = threadIdx.x;
    const int tx = t & 15, ty = t >> 4;
    float acc[4][4] = {};
    for (int k0 = 0; k0 < 256; k0 += 16) {
        #pragma unroll
        for (int i = 0; i < 4; ++i) {
            int idx = t + i * 256;
            int mm = idx >> 4, kk = idx & 15;
            As[kk][mm] = x[(size_t)(m0 + mm) * 256 + k0 + kk];
            Bs[kk][mm] = w[(size_t)(n0 + mm) * 256 + k0 + kk];
        }
        __syncthreads();
        #pragma unroll
        for (int kk = 0; kk < 16; ++kk) {
            float4 av = *(const float4*)&As[kk][ty * 4];
            float4 bv = *(const float4*)&Bs[kk][tx * 4];
            float a[4] = {av.x, av.y, av.z, av.w};
            float bb[4] = {bv.x, bv.y, bv.z, bv.w};
            #pragma unroll
            for (int i = 0; i < 4; ++i)
                #pragma unroll
                for (int j = 0; j < 4; ++j)
                    acc[i][j] += a[i] * bb[j];
        }
        __syncthreads();
    }
    #pragma unroll
    for (int i = 0; i < 4; ++i) {
        int m = m0 + ty * 4 + i;
        #pragma unroll
        for (int j = 0; j < 4; ++j) {
            int e = n0 + tx * 4 + j;
            qkv[(size_t)m * 768 + e] = __float2bfloat16(acc[i][j] + bias[e]);
        }
    }
}

// =====================================================================
// K2: flash-style attention, one wave per query row (cold path)
//   O[b,n,:] = softmax(q_n . K^T) @ V
// =====================================================================
__global__ __launch_bounds__(256)
void attn_kernel(const __hip_bfloat16* __restrict__ qkvh,
                 const float* __restrict__ gamma, float* __restrict__ O)
{
    if (gamma[0] == 0.0f) return;
    const unsigned short* qkv = (const unsigned short*)qkvh;
    const int b = blockIdx.y;
    const int n = blockIdx.x * 4 + (threadIdx.x >> 6);
    const int lane = threadIdx.x & 63;
    const size_t base = (size_t)b * SEQ * 768;
    const unsigned short* qp = qkv + base + (size_t)n * 768 + lane * 4;
    float q0 = bf2f(qp[0]), q1 = bf2f(qp[1]), q2 = bf2f(qp[2]), q3 = bf2f(qp[3]);
    float m = -INFINITY, l = 0.f, a0 = 0.f, a1 = 0.f, a2 = 0.f, a3 = 0.f;
    for (int j = 0; j < SEQ; ++j) {
        const unsigned short* kp = qkv + base + (size_t)j * 768 + 256 + lane * 4;
        float s = q0 * bf2f(kp[0]) + q1 * bf2f(kp[1]) + q2 * bf2f(kp[2]) + q3 * bf2f(kp[3]);
        #pragma unroll
        for (int off = 32; off; off >>= 1) s += __shfl_xor(s, off);
        float mn = fmaxf(m, s);
        float corr = __expf(m - mn);
        float p = __expf(s - mn);
        l = l * corr + p;
        const unsigned short* vp = qkv + base + (size_t)j * 768 + 512 + lane * 4;
        a0 = a0 * corr + p * bf2f(vp[0]);
        a1 = a1 * corr + p * bf2f(vp[1]);
        a2 = a2 * corr + p * bf2f(vp[2]);
        a3 = a3 * corr + p * bf2f(vp[3]);
        m = mn;
    }
    float inv = 1.f / l;
    float* op = O + ((size_t)b * SEQ + n) * 256 + lane * 4;
    op[0] = a0 * inv; op[1] = a1 * inv; op[2] = a2 * inv; op[3] = a3 * inv;
}

// =====================================================================
// K3: dynamic_adj = sigmoid(fc_w @ concat(gamma*O + x, x) + fc_b)
//   adj[b,o,l] = sigmoid( sum_n (w1+w2)[o,n]*x[b,n,l] + g*w1[o,n]*O[b,n,l] + fc_b[o] )
//   per batch: M=256 (o), N=256 (l), K=1024 (n)
// =====================================================================
__global__ __launch_bounds__(256)
void fc_adj_gemm(const float* __restrict__ x, const float* __restrict__ O,
                 const float* __restrict__ fc_w, const float* __restrict__ fc_b,
                 const float* __restrict__ gamma, float* __restrict__ adj)
{
    __shared__ float As [16][68];
    __shared__ float Bs [16][68];
    __shared__ float As2[16][68];
    __shared__ float Bs2[16][68];
    const float g = gamma[0];
    const bool use_o = (g != 0.0f);
    const int b  = blockIdx.z;
    const int m0 = blockIdx.y * 64;
    const int n0 = blockIdx.x * 64;
    const int t  = threadIdx.x;
    const int tx = t & 15, ty = t >> 4;
    float acc[4][4] = {};
    for (int k0 = 0; k0 < 1024; k0 += 16) {
        #pragma unroll
        for (int i = 0; i < 4; ++i) {
            int idx = t + i * 256;
            int mm = idx >> 4, kk = idx & 15;
            float w1 = fc_w[(size_t)(m0 + mm) * 2048 + k0 + kk];
            float w2 = fc_w[(size_t)(m0 + mm) * 2048 + 1024 + k0 + kk];
            As[kk][mm] = w1 + w2;
            int nn = idx & 63, kk2 = idx >> 6;
            Bs[kk2][nn] = x[((size_t)b * SEQ + k0 + kk2) * 256 + n0 + nn];
            if (use_o) {
                As2[kk][mm]  = g * w1;
                Bs2[kk2][nn] = O[((size_t)b * SEQ + k0 + kk2) * 256 + n0 + nn];
            }
        }
        __syncthreads();
        #pragma unroll
        for (int kk = 0; kk < 16; ++kk) {
            float4 av = *(const float4*)&As[kk][ty * 4];
            float4 bv = *(const float4*)&Bs[kk][tx * 4];
            float a[4] = {av.x, av.y, av.z, av.w};
            float bb[4] = {bv.x, bv.y, bv.z, bv.w};
            #pragma unroll
            for (int i = 0; i < 4; ++i)
                #pragma unroll
                for (int j = 0; j < 4; ++j)
                    acc[i][j] += a[i] * bb[j];
            if (use_o) {
                float4 av2 = *(const float4*)&As2[kk][ty * 4];
                float4 bv2 = *(const float4*)&Bs2[kk][tx * 4];
                float a2[4] = {av2.x, av2.y, av2.z, av2.w};
                float b2[4] = {bv2.x, bv2.y, bv2.z, bv2.w};
                #pragma unroll
                for (int i = 0; i < 4; ++i)
                    #pragma unroll
                    for (int j = 0; j < 4; ++j)
                        acc[i][j] += a2[i] * b2[j];
            }
        }
        __syncthreads();
    }
    #pragma unroll
    for (int i = 0; i < 4; ++i) {
        int o = m0 + ty * 4 + i;
        float fb = fc_b[o];
        float4 v;
        v.x = 1.f / (1.f + __expf(-(acc[i][0] + fb)));
        v.y = 1.f / (1.f + __expf(-(acc[i][1] + fb)));
        v.z = 1.f / (1.f + __expf(-(acc[i][2] + fb)));
        v.w = 1.f / (1.f + __expf(-(acc[i][3] + fb)));
        *(float4*)&adj[((size_t)b * 256 + o) * 256 + n0 + tx * 4] = v;
    }
}

// =====================================================================
// K4: y1[b,n,l] = leaky( sum_d x[b,n,d] * adj[b,d,l] )
//   per batch: M=1024, N=256, K=256
// =====================================================================
__global__ __launch_bounds__(256)
void y1_gemm(const float* __restrict__ x, const float* __restrict__ adj,
             float* __restrict__ y1)
{
    __shared__ float As[16][68];
    __shared__ float Bs[16][68];
    const int b  = blockIdx.z;
    const int m0 = blockIdx.y * 64;
    const int n0 = blockIdx.x * 64;
    const int t  = threadIdx.x;
    const int tx = t & 15, ty = t >> 4;
    float acc[4][4] = {};
    for (int k0 = 0; k0 < 256; k0 += 16) {
        #pragma unroll
        for (int i = 0; i < 4; ++i) {
            int idx = t + i * 256;
            int mm = idx >> 4, kk = idx & 15;
            As[kk][mm] = x[((size_t)b * SEQ + m0 + mm) * 256 + k0 + kk];
            int nn = idx & 63, kk2 = idx >> 6;
            Bs[kk2][nn] = adj[((size_t)b * 256 + k0 + kk2) * 256 + n0 + nn];
        }
        __syncthreads();
        #pragma unroll
        for (int kk = 0; kk < 16; ++kk) {
            float4 av = *(const float4*)&As[kk][ty * 4];
            float4 bv = *(const float4*)&Bs[kk][tx * 4];
            float a[4] = {av.x, av.y, av.z, av.w};
            float bb[4] = {bv.x, bv.y, bv.z, bv.w};
            #pragma unroll
            for (int i = 0; i < 4; ++i)
                #pragma unroll
                for (int j = 0; j < 4; ++j)
                    acc[i][j] += a[i] * bb[j];
        }
        __syncthreads();
    }
    #pragma unroll
    for (int i = 0; i < 4; ++i) {
        int m = m0 + ty * 4 + i;
        float4 v;
        v.x = leaky(acc[i][0]); v.y = leaky(acc[i][1]);
        v.z = leaky(acc[i][2]); v.w = leaky(acc[i][3]);
        *(float4*)&y1[((size_t)b * SEQ + m) * 256 + n0 + tx * 4] = v;
    }
}

// =====================================================================
// K5: out[b,o,l] = leaky( sum_c dw_w[o,c] * y1[b,c,l] + dw_b[o] )
//   per batch: M=1024, N=256, K=1024 (dw_w shared across batches)
// =====================================================================
__global__ __launch_bounds__(256)
void dw_gemm(const float* __restrict__ y1, const float* __restrict__ dw_w,
             const float* __restrict__ dw_b, float* __restrict__ out)
{
    __shared__ float As[16][68];
    __shared__ float Bs[16][68];
    const int b  = blockIdx.z;
    const int m0 = blockIdx.y * 64;
    const int n0 = blockIdx.x * 64;
    const int t  = threadIdx.x;
    const int tx = t & 15, ty = t >> 4;
    float acc[4][4] = {};
    for (int k0 = 0; k0 < 1024; k0 += 16) {
        #pragma unroll
        for (int i = 0; i < 4; ++i) {
            int idx = t + i * 256;
            int mm = idx >> 4, kk = idx & 15;
            As[kk][mm] = dw_w[(size_t)(m0 + mm) * 1024 + k0 + kk];
            int nn = idx & 63, kk2 = idx >> 6;
            Bs[kk2][nn] = y1[((size_t)b * SEQ + k0 + kk2) * 256 + n0 + nn];
        }
        __syncthreads();
        #pragma unroll
        for (int kk = 0; kk < 16; ++kk) {
            float4 av = *(const float4*)&As[kk][ty * 4];
            float4 bv = *(const float4*)&Bs[kk][tx * 4];
            float a[4] = {av.x, av.y, av.z, av.w};
            float bb[4] = {bv.x, bv.y, bv.z, bv.w};
            #pragma unroll
            for (int i = 0; i < 4; ++i)
                #pragma unroll
                for (int j = 0; j < 4; ++j)
                    acc[i][j] += a[i] * bb[j];
        }
        __syncthreads();
    }
    #pragma unroll
    for (int i = 0; i < 4; ++i) {
        int o = m0 + ty * 4 + i;
        float db = dw_b[o];
        float4 v;
        v.x = leaky(acc[i][0] + db); v.y = leaky(acc[i][1] + db);
        v.z = leaky(acc[i][2] + db); v.w = leaky(acc[i][3] + db);
        *(float4*)&out[((size_t)b * 1024 + o) * 256 + n0 + tx * 4] = v;
    }
}

// =====================================================================
extern "C" void kernel_launch(void* const* d_in, const int* in_sizes, int n_in,
                              void* d_out, int out_size, void* d_ws, size_t ws_size,
                              hipStream_t stream)
{
    (void)in_sizes; (void)n_in; (void)out_size; (void)ws_size;
    const float* x     = (const float*)d_in[0];
    const float* qkv_w = (const float*)d_in[1];
    const float* qkv_b = (const float*)d_in[2];
    const float* gamma = (const float*)d_in[3];
    const float* fc_w  = (const float*)d_in[4];
    const float* fc_b  = (const float*)d_in[5];
    const float* dw_w  = (const float*)d_in[6];
    const float* dw_b  = (const float*)d_in[7];
    float* out = (float*)d_out;

    // Workspace layout: hot (always-used) buffers first.
    char* ws = (char*)d_ws;
    float* adj = (float*)ws;                                      // 64*256*256  f32 (16.8 MB)
    float* y1  = (float*)(ws + (size_t)NB * 256 * 256 * 4);       // 64*1024*256 f32 (67.1 MB)
    __hip_bfloat16* qkv = (__hip_bfloat16*)(ws
                       + (size_t)NB * 256 * 256 * 4
                       + (size_t)NB * SEQ * 256 * 4);             // 64*1024*768 bf16 (100.7 MB, cold)
    float* O   = (float*)((char*)qkv + (size_t)NB * SEQ * 768 * 2); // 64*1024*256 f32 (67.1 MB, cold)

    // Cold path (gamma != 0): QKV projection + attention.
    qkv_gemm  <<<dim3(12, 1024),    256, 0, stream>>>(x, qkv_w, qkv_b, gamma, qkv);
    attn_kernel<<<dim3(SEQ / 4, NB), 256, 0, stream>>>(qkv, gamma, O);

    // Hot path.
    fc_adj_gemm<<<dim3(4, 4, NB),  256, 0, stream>>>(x, O, fc_w, fc_b, gamma, adj);
    y1_gemm    <<<dim3(4, 16, NB), 256, 0, stream>>>(x, adj, y1);
    dw_gemm    <<<dim3(4, 16, NB), 256, 0, stream>>>(y1, dw_w, dw_b, out);
}

// Round 2
// 270.833 us; speedup vs baseline: 3.2965x; 3.2965x over previous
//
#include <hip/hip_runtime.h>
#include <hip/hip_bf16.h>

#define NEG_SLOPE 0.2f

static constexpr int NB  = 64;
static constexpr int SEQ = 1024;

typedef __attribute__((ext_vector_type(8))) short  s16x8;
typedef __attribute__((ext_vector_type(4))) float  f32x4;
typedef __attribute__((ext_vector_type(8))) unsigned short u16x8;
typedef __attribute__((ext_vector_type(4))) unsigned short u16x4;

typedef __attribute__((address_space(1))) void gvoid;
typedef __attribute__((address_space(3))) void lvoid;

__device__ __forceinline__ float bf2f(unsigned short u) {
    return __uint_as_float(((unsigned int)u) << 16);
}
__device__ __forceinline__ unsigned short f2bf(float f) {
    __hip_bfloat16 h = __float2bfloat16(f);
    return *reinterpret_cast<unsigned short*>(&h);
}
__device__ __forceinline__ float leaky(float v) {
    return v >= 0.0f ? v : NEG_SLOPE * v;
}
// global -> LDS direct DMA, 16B per lane. Dest must be wave-uniform; HW adds lane*16.
__device__ __forceinline__ void gload_lds16(const void* g, void* l) {
    __builtin_amdgcn_global_load_lds((const gvoid*)(size_t)g,
                                     (lvoid*)(unsigned int)(size_t)l, 16, 0, 0);
}

// =====================================================================
// Cold path (gamma != 0 only): QKV projection + flash attention -> O
// =====================================================================
__global__ __launch_bounds__(256)
void qkv_gemm(const float* __restrict__ x, const float* __restrict__ w,
              const float* __restrict__ bias, const float* __restrict__ gamma,
              __hip_bfloat16* __restrict__ qkv)
{
    if (gamma[0] == 0.0f) return;
    __shared__ float As[16][68];
    __shared__ float Bs[16][68];
    const int m0 = blockIdx.y * 64;
    const int n0 = blockIdx.x * 64;
    const int t  = threadIdx.x;
    const int tx = t & 15, ty = t >> 4;
    float acc[4][4] = {};
    for (int k0 = 0; k0 < 256; k0 += 16) {
        #pragma unroll
        for (int i = 0; i < 4; ++i) {
            int idx = t + i * 256;
            int mm = idx >> 4, kk = idx & 15;
            As[kk][mm] = x[(size_t)(m0 + mm) * 256 + k0 + kk];
            Bs[kk][mm] = w[(size_t)(n0 + mm) * 256 + k0 + kk];
        }
        __syncthreads();
        #pragma unroll
        for (int kk = 0; kk < 16; ++kk) {
            float4 av = *(const float4*)&As[kk][ty * 4];
            float4 bv = *(const float4*)&Bs[kk][tx * 4];
            float a[4] = {av.x, av.y, av.z, av.w};
            float bb[4] = {bv.x, bv.y, bv.z, bv.w};
            #pragma unroll
            for (int i = 0; i < 4; ++i)
                #pragma unroll
                for (int j = 0; j < 4; ++j)
                    acc[i][j] += a[i] * bb[j];
        }
        __syncthreads();
    }
    #pragma unroll
    for (int i = 0; i < 4; ++i) {
        int m = m0 + ty * 4 + i;
        #pragma unroll
        for (int j = 0; j < 4; ++j) {
            int e = n0 + tx * 4 + j;
            qkv[(size_t)m * 768 + e] = __float2bfloat16(acc[i][j] + bias[e]);
        }
    }
}

__global__ __launch_bounds__(256)
void attn_kernel(const __hip_bfloat16* __restrict__ qkvh,
                 const float* __restrict__ gamma, float* __restrict__ O)
{
    if (gamma[0] == 0.0f) return;
    const unsigned short* qkv = (const unsigned short*)qkvh;
    const int b = blockIdx.y;
    const int n = blockIdx.x * 4 + (threadIdx.x >> 6);
    const int lane = threadIdx.x & 63;
    const size_t base = (size_t)b * SEQ * 768;
    const unsigned short* qp = qkv + base + (size_t)n * 768 + lane * 4;
    float q0 = bf2f(qp[0]), q1 = bf2f(qp[1]), q2 = bf2f(qp[2]), q3 = bf2f(qp[3]);
    float m = -INFINITY, l = 0.f, a0 = 0.f, a1 = 0.f, a2 = 0.f, a3 = 0.f;
    for (int j = 0; j < SEQ; ++j) {
        const unsigned short* kp = qkv + base + (size_t)j * 768 + 256 + lane * 4;
        float s = q0 * bf2f(kp[0]) + q1 * bf2f(kp[1]) + q2 * bf2f(kp[2]) + q3 * bf2f(kp[3]);
        #pragma unroll
        for (int off = 32; off; off >>= 1) s += __shfl_xor(s, off);
        float mn = fmaxf(m, s);
        float corr = __expf(m - mn);
        float p = __expf(s - mn);
        l = l * corr + p;
        const unsigned short* vp = qkv + base + (size_t)j * 768 + 512 + lane * 4;
        a0 = a0 * corr + p * bf2f(vp[0]);
        a1 = a1 * corr + p * bf2f(vp[1]);
        a2 = a2 * corr + p * bf2f(vp[2]);
        a3 = a3 * corr + p * bf2f(vp[3]);
        m = mn;
    }
    float inv = 1.f / l;
    float* op = O + ((size_t)b * SEQ + n) * 256 + lane * 4;
    op[0] = a0 * inv; op[1] = a1 * inv; op[2] = a2 * inv; op[3] = a3 * inv;
}

// =====================================================================
// conv_xcT: builds (per batch b)
//   xcT[b][l][nc] (bf16, [256][2048]): nc<1024 -> gamma*O[b][nc][l]+x[b][nc][l]
//                                      nc>=1024 -> x[b][nc-1024][l]
//   x_bf[b][n][d] (bf16, straight copy of x)
// =====================================================================
__global__ __launch_bounds__(256)
void conv_xcT(const float* __restrict__ x, const float* __restrict__ O,
              const float* __restrict__ gamma,
              unsigned short* __restrict__ xcT, unsigned short* __restrict__ x_bf)
{
    __shared__ float xs [64][68];
    __shared__ float xgs[64][68];
    const int b  = blockIdx.z;
    const int n0 = blockIdx.x * 64;
    const int l0 = blockIdx.y * 64;
    const int t  = threadIdx.x;
    const float g = gamma[0];
    const int cl = (t & 15) * 4;
    #pragma unroll
    for (int i = 0; i < 4; ++i) {
        int row = (t >> 4) + i * 16;
        size_t gi = ((size_t)b * SEQ + n0 + row) * 256 + l0 + cl;
        float4 xv = *(const float4*)(x + gi);
        float4 xg = xv;
        if (g != 0.0f) {                 // uniform branch; O never read when gamma==0
            float4 ov = *(const float4*)(O + gi);
            xg.x += g * ov.x; xg.y += g * ov.y; xg.z += g * ov.z; xg.w += g * ov.w;
        }
        u16x4 xb = { f2bf(xv.x), f2bf(xv.y), f2bf(xv.z), f2bf(xv.w) };
        *(u16x4*)(x_bf + gi) = xb;
        xs [row][cl+0] = xv.x; xs [row][cl+1] = xv.y; xs [row][cl+2] = xv.z; xs [row][cl+3] = xv.w;
        xgs[row][cl+0] = xg.x; xgs[row][cl+1] = xg.y; xgs[row][cl+2] = xg.z; xgs[row][cl+3] = xg.w;
    }
    __syncthreads();
    const int lrow = t >> 2;
    const int nseg = (t & 3) * 16;
    size_t obase = ((size_t)b * 256 + l0 + lrow) * 2048 + n0 + nseg;
    #pragma unroll
    for (int h = 0; h < 2; ++h) {
        u16x8 v1, v2;
        #pragma unroll
        for (int j = 0; j < 8; ++j) {
            v1[j] = f2bf(xgs[nseg + h * 8 + j][lrow]);
            v2[j] = f2bf(xs [nseg + h * 8 + j][lrow]);
        }
        *(u16x8*)(xcT + obase + h * 8)        = v1;
        *(u16x8*)(xcT + obase + 1024 + h * 8) = v2;
    }
}

// =====================================================================
// conv_w: fc_w (256x2048) and dw_w (1024x1024) -> bf16
// =====================================================================
__global__ __launch_bounds__(256)
void conv_w(const float* __restrict__ fc_w, const float* __restrict__ dw_w,
            unsigned short* __restrict__ fc_w_bf, unsigned short* __restrict__ dw_w_bf)
{
    int idx = blockIdx.x * 256 + threadIdx.x;   // float4 index
    if (idx < 131072) {
        float4 v = *(const float4*)(fc_w + (size_t)idx * 4);
        u16x4 o = { f2bf(v.x), f2bf(v.y), f2bf(v.z), f2bf(v.w) };
        *(u16x4*)(fc_w_bf + (size_t)idx * 4) = o;
    } else {
        int j = idx - 131072;
        float4 v = *(const float4*)(dw_w + (size_t)j * 4);
        u16x4 o = { f2bf(v.x), f2bf(v.y), f2bf(v.z), f2bf(v.w) };
        *(u16x4*)(dw_w_bf + (size_t)j * 4) = o;
    }
}

// =====================================================================
// MFMA NT GEMM: C[m][n] = epi( sum_k A[m][k]*B[n][k] )
//   128x128 tile, BK=64, 4 waves each 64x64. XOR-swizzled LDS (T2).
//   EPI 0: sigmoid(acc+bias[col]) -> bf16   (fc adj)
//   EPI 1: leaky(acc)             -> bf16   (y1)
//   EPI 2: leaky(acc+bias[row])   -> f32    (dw, final output)
// =====================================================================
template<int EPI>
__global__ __launch_bounds__(256)
void gemm_nt(const unsigned short* __restrict__ A, long sA, int lda,
             const unsigned short* __restrict__ B, long sB, int ldb,
             void* __restrict__ Cv, long sC, int ldc,
             const float* __restrict__ bias, int K)
{
    __shared__ char smem[32768];
    char* As = smem;
    char* Bs = smem + 16384;
    const int bz = blockIdx.z;
    const int m0 = blockIdx.y * 128, n0 = blockIdx.x * 128;
    const int t = threadIdx.x, w = t >> 6, lane = t & 63;
    const unsigned short* Ag = A + (size_t)bz * sA;
    const unsigned short* Bg = B + (size_t)bz * sB;
    const int wm0 = (w >> 1) * 64, wn0 = (w & 1) * 64;
    f32x4 acc[4][4] = {};

    for (int k0 = 0; k0 < K; k0 += 64) {
        __syncthreads();
        #pragma unroll
        for (int i = 0; i < 4; ++i) {
            int chunk = i * 4 + w;                 // 1KB LDS chunk, wave-uniform
            int off = chunk * 1024 + lane * 16;    // this lane's LDS byte slot
            int r  = off >> 7;                     // tile row (128B rows)
            int cp = (off >> 4) & 7;               // swizzled 16B slot
            int c  = cp ^ (r & 7);                 // global 16B chunk (pre-swizzled source)
            gload_lds16(Ag + (size_t)(m0 + r) * lda + k0 + c * 8, As + chunk * 1024);
            gload_lds16(Bg + (size_t)(n0 + r) * ldb + k0 + c * 8, Bs + chunk * 1024);
        }
        __syncthreads();   // compiler drains vmcnt(0) before barrier -> tiles ready
        s16x8 af[4][2], bfr[4][2];
        #pragma unroll
        for (int mi = 0; mi < 4; ++mi)
            #pragma unroll
            for (int kk = 0; kk < 2; ++kk) {
                int ra = wm0 + mi * 16 + (lane & 15);
                int bca = (kk * 64 + ((lane >> 4) * 16)) ^ ((ra & 7) << 4);
                af[mi][kk] = *(const s16x8*)(As + ra * 128 + bca);
                int rb = wn0 + mi * 16 + (lane & 15);
                int bcb = (kk * 64 + ((lane >> 4) * 16)) ^ ((rb & 7) << 4);
                bfr[mi][kk] = *(const s16x8*)(Bs + rb * 128 + bcb);
            }
        #pragma unroll
        for (int mi = 0; mi < 4; ++mi)
            #pragma unroll
            for (int ni = 0; ni < 4; ++ni) {
                acc[mi][ni] = __builtin_amdgcn_mfma_f32_16x16x32_bf16(af[mi][0], bfr[ni][0], acc[mi][ni], 0, 0, 0);
                acc[mi][ni] = __builtin_amdgcn_mfma_f32_16x16x32_bf16(af[mi][1], bfr[ni][1], acc[mi][ni], 0, 0, 0);
            }
    }

    #pragma unroll
    for (int mi = 0; mi < 4; ++mi) {
        int row0 = m0 + wm0 + mi * 16 + ((lane >> 4) << 2);
        #pragma unroll
        for (int ni = 0; ni < 4; ++ni) {
            int col = n0 + wn0 + ni * 16 + (lane & 15);
            float bcol = (EPI == 0) ? bias[col] : 0.0f;
            #pragma unroll
            for (int j = 0; j < 4; ++j) {
                float v = acc[mi][ni][j];
                if (EPI == 0) {
                    v = 1.0f / (1.0f + __expf(-(v + bcol)));
                    ((unsigned short*)Cv)[(size_t)bz * sC + (size_t)(row0 + j) * ldc + col] = f2bf(v);
                } else if (EPI == 1) {
                    v = leaky(v);
                    ((unsigned short*)Cv)[(size_t)bz * sC + (size_t)(row0 + j) * ldc + col] = f2bf(v);
                } else {
                    v = leaky(v + bias[row0 + j]);
                    ((float*)Cv)[(size_t)bz * sC + (size_t)(row0 + j) * ldc + col] = v;
                }
            }
        }
    }
}

// =====================================================================
extern "C" void kernel_launch(void* const* d_in, const int* in_sizes, int n_in,
                              void* d_out, int out_size, void* d_ws, size_t ws_size,
                              hipStream_t stream)
{
    (void)in_sizes; (void)n_in; (void)out_size; (void)ws_size;
    const float* x     = (const float*)d_in[0];
    const float* qkv_w = (const float*)d_in[1];
    const float* qkv_b = (const float*)d_in[2];
    const float* gamma = (const float*)d_in[3];
    const float* fc_w  = (const float*)d_in[4];
    const float* fc_b  = (const float*)d_in[5];
    const float* dw_w  = (const float*)d_in[6];
    const float* dw_b  = (const float*)d_in[7];
    float* out = (float*)d_out;

    char* ws = (char*)d_ws;
    unsigned short* xcT  = (unsigned short*)(ws);                 // 67,108,864 B
    unsigned short* x_bf = (unsigned short*)(ws + 67108864);      // 33,554,432 B
    unsigned short* adjT = (unsigned short*)(ws + 100663296);     //  8,388,608 B
    unsigned short* y1T  = (unsigned short*)(ws + 109051904);     // 33,554,432 B
    unsigned short* fcwb = (unsigned short*)(ws + 142606336);     //  1,048,576 B
    unsigned short* dwwb = (unsigned short*)(ws + 143654912);     //  2,097,152 B
    float*          O    = (float*)        (ws + 145752064);      // 67,108,864 B
    __hip_bfloat16* qkv  = (__hip_bfloat16*)(ws);                 // cold; aliases xcT+x_bf (dead before convT)

    // Cold path (no-ops when gamma == 0).
    qkv_gemm   <<<dim3(12, 1024), 256, 0, stream>>>(x, qkv_w, qkv_b, gamma, qkv);
    attn_kernel<<<dim3(256, NB),  256, 0, stream>>>(qkv, gamma, O);

    // Conversions.
    conv_w  <<<1536, 256, 0, stream>>>(fc_w, dw_w, fcwb, dwwb);
    conv_xcT<<<dim3(16, 4, NB), 256, 0, stream>>>(x, O, gamma, xcT, x_bf);

    // adjT[b][l][o] = sigmoid( xcT[b] . fc_w^T + fc_b[o] )    M=256 N=256 K=2048
    gemm_nt<0><<<dim3(2, 2, NB), 256, 0, stream>>>(xcT, 524288, 2048,
                                                   fcwb, 0, 2048,
                                                   adjT, 65536, 256, fc_b, 2048);
    // y1T[b][l][n] = leaky( adjT[b] . x_bf[b]^T )             M=256 N=1024 K=256
    gemm_nt<1><<<dim3(8, 2, NB), 256, 0, stream>>>(adjT, 65536, 256,
                                                   x_bf, 262144, 256,
                                                   y1T, 262144, 1024, nullptr, 256);
    // out[b][o][l] = leaky( dw_w . y1T[b]^T + dw_b[o] )       M=1024 N=256 K=1024
    gemm_nt<2><<<dim3(2, 8, NB), 256, 0, stream>>>(dwwb, 0, 1024,
                                                   y1T, 262144, 1024,
                                                   out, 262144, 256, dw_b, 1024);
}

// Round 3
// 232.125 us; speedup vs baseline: 3.8463x; 1.1668x over previous
//
#include <hip/hip_runtime.h>
#include <hip/hip_bf16.h>

#define NEG_SLOPE 0.2f

static constexpr int NB  = 64;
static constexpr int SEQ = 1024;

typedef __attribute__((ext_vector_type(8))) short  s16x8;
typedef __attribute__((ext_vector_type(4))) float  f32x4;
typedef __attribute__((ext_vector_type(8))) unsigned short u16x8;
typedef __attribute__((ext_vector_type(4))) unsigned short u16x4;

typedef __attribute__((address_space(1))) void gvoid;
typedef __attribute__((address_space(3))) void lvoid;

__device__ __forceinline__ float bf2f(unsigned short u) {
    return __uint_as_float(((unsigned int)u) << 16);
}
__device__ __forceinline__ unsigned short f2bf(float f) {
    __hip_bfloat16 h = __float2bfloat16(f);
    return *reinterpret_cast<unsigned short*>(&h);
}
__device__ __forceinline__ float leaky(float v) {
    return v >= 0.0f ? v : NEG_SLOPE * v;
}
__device__ __forceinline__ void gload_lds16(const void* g, void* l) {
    __builtin_amdgcn_global_load_lds((const gvoid*)(size_t)g,
                                     (lvoid*)(unsigned int)(size_t)l, 16, 0, 0);
}

// =====================================================================
// Cold path (gamma != 0 only): QKV projection + flash attention -> O
// =====================================================================
__global__ __launch_bounds__(256)
void qkv_gemm(const float* __restrict__ x, const float* __restrict__ w,
              const float* __restrict__ bias, const float* __restrict__ gamma,
              __hip_bfloat16* __restrict__ qkv)
{
    if (gamma[0] == 0.0f) return;
    __shared__ float As[16][68];
    __shared__ float Bs[16][68];
    const int m0 = blockIdx.y * 64;
    const int n0 = blockIdx.x * 64;
    const int t  = threadIdx.x;
    const int tx = t & 15, ty = t >> 4;
    float acc[4][4] = {};
    for (int k0 = 0; k0 < 256; k0 += 16) {
        #pragma unroll
        for (int i = 0; i < 4; ++i) {
            int idx = t + i * 256;
            int mm = idx >> 4, kk = idx & 15;
            As[kk][mm] = x[(size_t)(m0 + mm) * 256 + k0 + kk];
            Bs[kk][mm] = w[(size_t)(n0 + mm) * 256 + k0 + kk];
        }
        __syncthreads();
        #pragma unroll
        for (int kk = 0; kk < 16; ++kk) {
            float4 av = *(const float4*)&As[kk][ty * 4];
            float4 bv = *(const float4*)&Bs[kk][tx * 4];
            float a[4] = {av.x, av.y, av.z, av.w};
            float bb[4] = {bv.x, bv.y, bv.z, bv.w};
            #pragma unroll
            for (int i = 0; i < 4; ++i)
                #pragma unroll
                for (int j = 0; j < 4; ++j)
                    acc[i][j] += a[i] * bb[j];
        }
        __syncthreads();
    }
    #pragma unroll
    for (int i = 0; i < 4; ++i) {
        int m = m0 + ty * 4 + i;
        #pragma unroll
        for (int j = 0; j < 4; ++j) {
            int e = n0 + tx * 4 + j;
            qkv[(size_t)m * 768 + e] = __float2bfloat16(acc[i][j] + bias[e]);
        }
    }
}

__global__ __launch_bounds__(256)
void attn_kernel(const __hip_bfloat16* __restrict__ qkvh,
                 const float* __restrict__ gamma, float* __restrict__ O)
{
    if (gamma[0] == 0.0f) return;
    const unsigned short* qkv = (const unsigned short*)qkvh;
    const int b = blockIdx.y;
    const int n = blockIdx.x * 4 + (threadIdx.x >> 6);
    const int lane = threadIdx.x & 63;
    const size_t base = (size_t)b * SEQ * 768;
    const unsigned short* qp = qkv + base + (size_t)n * 768 + lane * 4;
    float q0 = bf2f(qp[0]), q1 = bf2f(qp[1]), q2 = bf2f(qp[2]), q3 = bf2f(qp[3]);
    float m = -INFINITY, l = 0.f, a0 = 0.f, a1 = 0.f, a2 = 0.f, a3 = 0.f;
    for (int j = 0; j < SEQ; ++j) {
        const unsigned short* kp = qkv + base + (size_t)j * 768 + 256 + lane * 4;
        float s = q0 * bf2f(kp[0]) + q1 * bf2f(kp[1]) + q2 * bf2f(kp[2]) + q3 * bf2f(kp[3]);
        #pragma unroll
        for (int off = 32; off; off >>= 1) s += __shfl_xor(s, off);
        float mn = fmaxf(m, s);
        float corr = __expf(m - mn);
        float p = __expf(s - mn);
        l = l * corr + p;
        const unsigned short* vp = qkv + base + (size_t)j * 768 + 512 + lane * 4;
        a0 = a0 * corr + p * bf2f(vp[0]);
        a1 = a1 * corr + p * bf2f(vp[1]);
        a2 = a2 * corr + p * bf2f(vp[2]);
        a3 = a3 * corr + p * bf2f(vp[3]);
        m = mn;
    }
    float inv = 1.f / l;
    float* op = O + ((size_t)b * SEQ + n) * 256 + lane * 4;
    op[0] = a0 * inv; op[1] = a1 * inv; op[2] = a2 * inv; op[3] = a3 * inv;
}

// Cold: OT[b][l][n] = bf16( O[b][n][l] )   (flat [16384][1024])
__global__ __launch_bounds__(256)
void conv_OT(const float* __restrict__ O, const float* __restrict__ gamma,
             unsigned short* __restrict__ OT)
{
    if (gamma[0] == 0.0f) return;
    __shared__ float xs[64][68];
    const int b  = blockIdx.z;
    const int n0 = blockIdx.x * 64;
    const int l0 = blockIdx.y * 64;
    const int t  = threadIdx.x;
    const int cl = (t & 15) * 4;
    #pragma unroll
    for (int i = 0; i < 4; ++i) {
        int row = (t >> 4) + i * 16;
        size_t gi = ((size_t)b * SEQ + n0 + row) * 256 + l0 + cl;
        float4 xv = *(const float4*)(O + gi);
        xs[row][cl+0] = xv.x; xs[row][cl+1] = xv.y;
        xs[row][cl+2] = xv.z; xs[row][cl+3] = xv.w;
    }
    __syncthreads();
    const int lrow = t >> 2;
    const int nseg = (t & 3) * 16;
    size_t obase = ((size_t)b * 256 + l0 + lrow) * 1024 + n0 + nseg;
    #pragma unroll
    for (int h = 0; h < 2; ++h) {
        u16x8 v;
        #pragma unroll
        for (int j = 0; j < 8; ++j) v[j] = f2bf(xs[nseg + h * 8 + j][lrow]);
        *(u16x8*)(OT + obase + h * 8) = v;
    }
}

// =====================================================================
// conv_xT: xT[b][l][n] = bf16(x[b][n][l])  (flat [16384][1024]),
//          x_bf[b][n][d] = bf16(x)         (straight copy)
// =====================================================================
__global__ __launch_bounds__(256)
void conv_xT(const float* __restrict__ x,
             unsigned short* __restrict__ xT, unsigned short* __restrict__ x_bf)
{
    __shared__ float xs[64][68];
    const int b  = blockIdx.z;
    const int n0 = blockIdx.x * 64;
    const int l0 = blockIdx.y * 64;
    const int t  = threadIdx.x;
    const int cl = (t & 15) * 4;
    #pragma unroll
    for (int i = 0; i < 4; ++i) {
        int row = (t >> 4) + i * 16;
        size_t gi = ((size_t)b * SEQ + n0 + row) * 256 + l0 + cl;
        float4 xv = *(const float4*)(x + gi);
        u16x4 xb = { f2bf(xv.x), f2bf(xv.y), f2bf(xv.z), f2bf(xv.w) };
        *(u16x4*)(x_bf + gi) = xb;
        xs[row][cl+0] = xv.x; xs[row][cl+1] = xv.y;
        xs[row][cl+2] = xv.z; xs[row][cl+3] = xv.w;
    }
    __syncthreads();
    const int lrow = t >> 2;
    const int nseg = (t & 3) * 16;
    size_t obase = ((size_t)b * 256 + l0 + lrow) * 1024 + n0 + nseg;
    #pragma unroll
    for (int h = 0; h < 2; ++h) {
        u16x8 v;
        #pragma unroll
        for (int j = 0; j < 8; ++j) v[j] = f2bf(xs[nseg + h * 8 + j][lrow]);
        *(u16x8*)(xT + obase + h * 8) = v;
    }
}

// =====================================================================
// prep_w: wsum = bf16(w1+w2) [256][1024], w1g = bf16(g*w1) [256][1024],
//         dww = bf16(dw_w)   [1024][1024]
// =====================================================================
__global__ __launch_bounds__(256)
void prep_w(const float* __restrict__ fc_w, const float* __restrict__ dw_w,
            const float* __restrict__ gamma,
            unsigned short* __restrict__ wsum, unsigned short* __restrict__ w1g,
            unsigned short* __restrict__ dww)
{
    int idx = blockIdx.x * 256 + threadIdx.x;   // float4 index
    if (idx < 65536) {                           // 256*1024/4
        float g = gamma[0];
        int o = idx >> 8, q = (idx & 255) * 4;
        float4 w1 = *(const float4*)(fc_w + (size_t)o * 2048 + q);
        float4 w2 = *(const float4*)(fc_w + (size_t)o * 2048 + 1024 + q);
        u16x4 s  = { f2bf(w1.x + w2.x), f2bf(w1.y + w2.y),
                     f2bf(w1.z + w2.z), f2bf(w1.w + w2.w) };
        u16x4 gq = { f2bf(g * w1.x), f2bf(g * w1.y), f2bf(g * w1.z), f2bf(g * w1.w) };
        *(u16x4*)(wsum + (size_t)idx * 4) = s;
        *(u16x4*)(w1g  + (size_t)idx * 4) = gq;
    } else {
        int j = idx - 65536;                     // 1024*1024/4 quads
        float4 v = *(const float4*)(dw_w + (size_t)j * 4);
        u16x4 o2 = { f2bf(v.x), f2bf(v.y), f2bf(v.z), f2bf(v.w) };
        *(u16x4*)(dww + (size_t)j * 4) = o2;
    }
}

// =====================================================================
// MFMA NT GEMM, 128x128 tile, BK=64, double-buffered LDS (T3-minimum):
//   STAGE(t+1) issued before compute(t); counted s_waitcnt vmcnt(8);
//   raw s_barrier + sched_barrier(0) fences (no vmcnt(0) drain per step).
//   EPI 0: sigmoid(acc+bias[col]) -> bf16   (adjT; + optional (A2,B2) pass)
//   EPI 1: leaky(acc)             -> bf16   (y1T)
//   EPI 2: leaky(acc+bias[row])   -> f32    (out)
// =====================================================================
template<int EPI, bool OPT2>
__global__ __launch_bounds__(256)
void gemm_nt(const unsigned short* __restrict__ A, long sA, int lda,
             const unsigned short* __restrict__ B, long sB, int ldb,
             const unsigned short* __restrict__ A2, int lda2,
             const unsigned short* __restrict__ B2, int ldb2,
             const float* __restrict__ gamma,
             void* __restrict__ Cv, long sC, int ldc,
             const float* __restrict__ bias, int K)
{
    __shared__ char smem[65536];       // 2 bufs x (A 16K + B 16K)
    const int bz = blockIdx.z;
    const int m0 = blockIdx.y * 128, n0 = blockIdx.x * 128;
    const int t = threadIdx.x, w = t >> 6, lane = t & 63;
    const int wm0 = (w >> 1) * 64, wn0 = (w & 1) * 64;
    f32x4 acc[4][4] = {};

    float g = 0.0f;
    if (OPT2) {
        g = gamma[0];
        asm volatile("s_waitcnt vmcnt(0)" ::: "memory");  // keep vmcnt counting clean
    }

    auto stage = [&](const unsigned short* Ag, int ldA,
                     const unsigned short* Bg, int ldB, int k0, int buf) {
        char* As = smem + buf * 32768;
        char* Bs = As + 16384;
        #pragma unroll
        for (int i = 0; i < 4; ++i) {
            int chunk = i * 4 + w;                 // wave-uniform 1KB LDS chunk
            int off = chunk * 1024 + lane * 16;
            int r = off >> 7;                      // tile row (128B = 64 bf16)
            int c = ((off >> 4) & 7) ^ (r & 7);    // pre-swizzled source 16B chunk
            gload_lds16(Ag + (size_t)(m0 + r) * ldA + k0 + c * 8, As + chunk * 1024);
            gload_lds16(Bg + (size_t)(n0 + r) * ldB + k0 + c * 8, Bs + chunk * 1024);
        }
    };

    auto compute = [&](int buf) {
        char* As = smem + buf * 32768;
        char* Bs = As + 16384;
        s16x8 af[4][2], bfr[4][2];
        #pragma unroll
        for (int mi = 0; mi < 4; ++mi)
            #pragma unroll
            for (int kk = 0; kk < 2; ++kk) {
                int ra = wm0 + mi * 16 + (lane & 15);
                int bca = (kk * 64 + ((lane >> 4) * 16)) ^ ((ra & 7) << 4);
                af[mi][kk] = *(const s16x8*)(As + ra * 128 + bca);
                int rb = wn0 + mi * 16 + (lane & 15);
                int bcb = (kk * 64 + ((lane >> 4) * 16)) ^ ((rb & 7) << 4);
                bfr[mi][kk] = *(const s16x8*)(Bs + rb * 128 + bcb);
            }
        #pragma unroll
        for (int mi = 0; mi < 4; ++mi)
            #pragma unroll
            for (int ni = 0; ni < 4; ++ni) {
                acc[mi][ni] = __builtin_amdgcn_mfma_f32_16x16x32_bf16(af[mi][0], bfr[ni][0], acc[mi][ni], 0, 0, 0);
                acc[mi][ni] = __builtin_amdgcn_mfma_f32_16x16x32_bf16(af[mi][1], bfr[ni][1], acc[mi][ni], 0, 0, 0);
            }
    };

    auto run = [&](const unsigned short* Ag, int ldA,
                   const unsigned short* Bg, int ldB, int Kl) {
        const int NT = Kl >> 6;
        stage(Ag, ldA, Bg, ldB, 0, 0);             // prologue: 8 loads in flight
        for (int tt = 0; tt < NT; ++tt) {
            int cur = tt & 1;
            if (tt + 1 < NT) {
                stage(Ag, ldA, Bg, ldB, (tt + 1) << 6, cur ^ 1);  // 16 in flight
                asm volatile("s_waitcnt vmcnt(8)" ::: "memory");  // oldest 8 (cur) landed
            } else {
                asm volatile("s_waitcnt vmcnt(0)" ::: "memory");
            }
            __builtin_amdgcn_s_barrier();          // all waves: cur fully staged
            __builtin_amdgcn_sched_barrier(0);
            compute(cur);
            __builtin_amdgcn_sched_barrier(0);
            __builtin_amdgcn_s_barrier();          // all waves done reading cur
        }
    };

    run(A + (size_t)bz * sA, lda, B + (size_t)bz * sB, ldb, K);
    if (OPT2) {
        if (g != 0.0f) run(A2, lda2, B2, ldb2, K);   // uniform; hot path skips
    }

    #pragma unroll
    for (int mi = 0; mi < 4; ++mi) {
        int row0 = m0 + wm0 + mi * 16 + ((lane >> 4) << 2);
        #pragma unroll
        for (int ni = 0; ni < 4; ++ni) {
            int col = n0 + wn0 + ni * 16 + (lane & 15);
            float bcol = (EPI == 0) ? bias[col] : 0.0f;
            #pragma unroll
            for (int j = 0; j < 4; ++j) {
                float v = acc[mi][ni][j];
                if (EPI == 0) {
                    v = 1.0f / (1.0f + __expf(-(v + bcol)));
                    ((unsigned short*)Cv)[(size_t)bz * sC + (size_t)(row0 + j) * ldc + col] = f2bf(v);
                } else if (EPI == 1) {
                    v = leaky(v);
                    ((unsigned short*)Cv)[(size_t)bz * sC + (size_t)(row0 + j) * ldc + col] = f2bf(v);
                } else {
                    v = leaky(v + bias[row0 + j]);
                    ((float*)Cv)[(size_t)bz * sC + (size_t)(row0 + j) * ldc + col] = v;
                }
            }
        }
    }
}

// =====================================================================
extern "C" void kernel_launch(void* const* d_in, const int* in_sizes, int n_in,
                              void* d_out, int out_size, void* d_ws, size_t ws_size,
                              hipStream_t stream)
{
    (void)in_sizes; (void)n_in; (void)out_size; (void)ws_size;
    const float* x     = (const float*)d_in[0];
    const float* qkv_w = (const float*)d_in[1];
    const float* qkv_b = (const float*)d_in[2];
    const float* gamma = (const float*)d_in[3];
    const float* fc_w  = (const float*)d_in[4];
    const float* fc_b  = (const float*)d_in[5];
    const float* dw_w  = (const float*)d_in[6];
    const float* dw_b  = (const float*)d_in[7];
    float* out = (float*)d_out;

    char* ws = (char*)d_ws;
    unsigned short* xT   = (unsigned short*)(ws);              // 33,554,432 B
    unsigned short* x_bf = (unsigned short*)(ws + 33554432);   // 33,554,432 B
    unsigned short* adjT = (unsigned short*)(ws + 67108864);   //  8,388,608 B
    unsigned short* y1T  = (unsigned short*)(ws + 75497472);   // 33,554,432 B
    unsigned short* wsum = (unsigned short*)(ws + 109051904);  //    524,288 B
    unsigned short* w1g  = (unsigned short*)(ws + 109576192);  //    524,288 B
    unsigned short* dwwb = (unsigned short*)(ws + 110100480);  //  2,097,152 B
    float*          O    = (float*)        (ws + 112197632);   // 67,108,864 B (cold)
    unsigned short* OT   = (unsigned short*)(ws + 179306496);  // 33,554,432 B (cold)
    __hip_bfloat16* qkv  = (__hip_bfloat16*)(ws);              // cold; aliases hot bufs (dead before conv_xT)

    // Cold path (no-ops when gamma == 0).
    qkv_gemm   <<<dim3(12, 1024), 256, 0, stream>>>(x, qkv_w, qkv_b, gamma, qkv);
    attn_kernel<<<dim3(256, NB),  256, 0, stream>>>(qkv, gamma, O);
    conv_OT    <<<dim3(16, 4, NB), 256, 0, stream>>>(O, gamma, OT);

    // Hot prep.
    prep_w <<<1280, 256, 0, stream>>>(fc_w, dw_w, gamma, wsum, w1g, dwwb);
    conv_xT<<<dim3(16, 4, NB), 256, 0, stream>>>(x, xT, x_bf);

    // adjT[(b,l)][o] = sigmoid( xT.wsum^T [+ OT.(g*w1)^T] + fc_b[o] )  M=16384 N=256 K=1024
    gemm_nt<0, true><<<dim3(2, 128, 1), 256, 0, stream>>>(
        xT, 0L, 1024, wsum, 0L, 1024, OT, 1024, w1g, 1024, gamma,
        adjT, 0L, 256, fc_b, 1024);
    // y1T[b][l][n] = leaky( adjT[b] . x_bf[b]^T )                      M=256 N=1024 K=256
    gemm_nt<1, false><<<dim3(8, 2, NB), 256, 0, stream>>>(
        adjT, 65536L, 256, x_bf, 262144L, 256, nullptr, 0, nullptr, 0, gamma,
        y1T, 262144L, 1024, nullptr, 256);
    // out[b][o][l] = leaky( dw_w . y1T[b]^T + dw_b[o] )                M=1024 N=256 K=1024
    gemm_nt<2, false><<<dim3(2, 8, NB), 256, 0, stream>>>(
        dwwb, 0L, 1024, y1T, 262144L, 1024, nullptr, 0, nullptr, 0, gamma,
        out, 262144L, 256, dw_b, 1024);
}

// Round 4
// 225.779 us; speedup vs baseline: 3.9544x; 1.0281x over previous
//
#include <hip/hip_runtime.h>
#include <hip/hip_bf16.h>

#define NEG_SLOPE 0.2f

static constexpr int NB  = 64;
static constexpr int SEQ = 1024;

typedef __attribute__((ext_vector_type(8))) short  s16x8;
typedef __attribute__((ext_vector_type(4))) float  f32x4;
typedef __attribute__((ext_vector_type(8))) unsigned short u16x8;
typedef __attribute__((ext_vector_type(4))) unsigned short u16x4;

typedef __attribute__((address_space(1))) void gvoid;
typedef __attribute__((address_space(3))) void lvoid;

__device__ __forceinline__ float bf2f(unsigned short u) {
    return __uint_as_float(((unsigned int)u) << 16);
}
__device__ __forceinline__ unsigned short f2bf(float f) {
    __hip_bfloat16 h = __float2bfloat16(f);
    return *reinterpret_cast<unsigned short*>(&h);
}
__device__ __forceinline__ float leaky(float v) {
    return v >= 0.0f ? v : NEG_SLOPE * v;
}
__device__ __forceinline__ void gload_lds16(const void* g, void* l) {
    __builtin_amdgcn_global_load_lds((const gvoid*)(size_t)g,
                                     (lvoid*)(unsigned int)(size_t)l, 16, 0, 0);
}
// Chunked XCD swizzle (T1): dispatch-consecutive blocks (same XCD mod 8)
// process contiguous work-ids. Requires nwg % 8 == 0 (all our grids comply).
__device__ __forceinline__ int xcd_swz(int bid, int nwg) {
    return (bid & 7) * (nwg >> 3) + (bid >> 3);
}

// =====================================================================
// Cold path (gamma != 0 only) — persistent grid-stride kernels so the
// gamma==0 early-exit costs ~1 dispatch of a small grid, not 10k+ WGs.
// =====================================================================
__global__ __launch_bounds__(256)
void qkv_gemm(const float* __restrict__ x, const float* __restrict__ w,
              const float* __restrict__ bias, const float* __restrict__ gamma,
              __hip_bfloat16* __restrict__ qkv)
{
    if (gamma[0] == 0.0f) return;
    __shared__ float As[16][68];
    __shared__ float Bs[16][68];
    const int t  = threadIdx.x;
    const int tx = t & 15, ty = t >> 4;
    for (int u = blockIdx.x; u < 12 * 1024; u += gridDim.x) {
        const int n0 = (u % 12) * 64;
        const int m0 = (u / 12) * 64;
        float acc[4][4] = {};
        for (int k0 = 0; k0 < 256; k0 += 16) {
            #pragma unroll
            for (int i = 0; i < 4; ++i) {
                int idx = t + i * 256;
                int mm = idx >> 4, kk = idx & 15;
                As[kk][mm] = x[(size_t)(m0 + mm) * 256 + k0 + kk];
                Bs[kk][mm] = w[(size_t)(n0 + mm) * 256 + k0 + kk];
            }
            __syncthreads();
            #pragma unroll
            for (int kk = 0; kk < 16; ++kk) {
                float4 av = *(const float4*)&As[kk][ty * 4];
                float4 bv = *(const float4*)&Bs[kk][tx * 4];
                float a[4] = {av.x, av.y, av.z, av.w};
                float bb[4] = {bv.x, bv.y, bv.z, bv.w};
                #pragma unroll
                for (int i = 0; i < 4; ++i)
                    #pragma unroll
                    for (int j = 0; j < 4; ++j)
                        acc[i][j] += a[i] * bb[j];
            }
            __syncthreads();
        }
        #pragma unroll
        for (int i = 0; i < 4; ++i) {
            int m = m0 + ty * 4 + i;
            #pragma unroll
            for (int j = 0; j < 4; ++j) {
                int e = n0 + tx * 4 + j;
                qkv[(size_t)m * 768 + e] = __float2bfloat16(acc[i][j] + bias[e]);
            }
        }
        __syncthreads();
    }
}

__global__ __launch_bounds__(256)
void attn_kernel(const __hip_bfloat16* __restrict__ qkvh,
                 const float* __restrict__ gamma, float* __restrict__ O)
{
    if (gamma[0] == 0.0f) return;
    const unsigned short* qkv = (const unsigned short*)qkvh;
    const int lane = threadIdx.x & 63;
    for (int u = blockIdx.x; u < NB * 256; u += gridDim.x) {
        const int b = u >> 8;
        const int n = (u & 255) * 4 + (threadIdx.x >> 6);
        const size_t base = (size_t)b * SEQ * 768;
        const unsigned short* qp = qkv + base + (size_t)n * 768 + lane * 4;
        float q0 = bf2f(qp[0]), q1 = bf2f(qp[1]), q2 = bf2f(qp[2]), q3 = bf2f(qp[3]);
        float m = -INFINITY, l = 0.f, a0 = 0.f, a1 = 0.f, a2 = 0.f, a3 = 0.f;
        for (int j = 0; j < SEQ; ++j) {
            const unsigned short* kp = qkv + base + (size_t)j * 768 + 256 + lane * 4;
            float s = q0 * bf2f(kp[0]) + q1 * bf2f(kp[1]) + q2 * bf2f(kp[2]) + q3 * bf2f(kp[3]);
            #pragma unroll
            for (int off = 32; off; off >>= 1) s += __shfl_xor(s, off);
            float mn = fmaxf(m, s);
            float corr = __expf(m - mn);
            float p = __expf(s - mn);
            l = l * corr + p;
            const unsigned short* vp = qkv + base + (size_t)j * 768 + 512 + lane * 4;
            a0 = a0 * corr + p * bf2f(vp[0]);
            a1 = a1 * corr + p * bf2f(vp[1]);
            a2 = a2 * corr + p * bf2f(vp[2]);
            a3 = a3 * corr + p * bf2f(vp[3]);
            m = mn;
        }
        float inv = 1.f / l;
        float* op = O + ((size_t)b * SEQ + n) * 256 + lane * 4;
        op[0] = a0 * inv; op[1] = a1 * inv; op[2] = a2 * inv; op[3] = a3 * inv;
    }
}

// Cold: OT[b][l][n] = bf16( O[b][n][l] )   (flat [16384][1024])
__global__ __launch_bounds__(256)
void conv_OT(const float* __restrict__ O, const float* __restrict__ gamma,
             unsigned short* __restrict__ OT)
{
    if (gamma[0] == 0.0f) return;
    __shared__ float xs[64][68];
    const int t  = threadIdx.x;
    const int cl = (t & 15) * 4;
    for (int u = blockIdx.x; u < 16 * 4 * NB; u += gridDim.x) {
        const int n0 = (u & 15) * 64;
        const int l0 = ((u >> 4) & 3) * 64;
        const int b  = u >> 6;
        #pragma unroll
        for (int i = 0; i < 4; ++i) {
            int row = (t >> 4) + i * 16;
            size_t gi = ((size_t)b * SEQ + n0 + row) * 256 + l0 + cl;
            float4 xv = *(const float4*)(O + gi);
            xs[row][cl+0] = xv.x; xs[row][cl+1] = xv.y;
            xs[row][cl+2] = xv.z; xs[row][cl+3] = xv.w;
        }
        __syncthreads();
        const int lrow = t >> 2;
        const int nseg = (t & 3) * 16;
        size_t obase = ((size_t)b * 256 + l0 + lrow) * 1024 + n0 + nseg;
        #pragma unroll
        for (int h = 0; h < 2; ++h) {
            u16x8 v;
            #pragma unroll
            for (int j = 0; j < 8; ++j) v[j] = f2bf(xs[nseg + h * 8 + j][lrow]);
            *(u16x8*)(OT + obase + h * 8) = v;
        }
        __syncthreads();
    }
}

// =====================================================================
// conv_xT: xT[b][l][n] = bf16(x[b][n][l])  (flat [16384][1024]),
//          x_bf[b][n][d] = bf16(x)         (straight copy)
// =====================================================================
__global__ __launch_bounds__(256)
void conv_xT(const float* __restrict__ x,
             unsigned short* __restrict__ xT, unsigned short* __restrict__ x_bf)
{
    __shared__ float xs[64][68];
    const int b  = blockIdx.z;
    const int n0 = blockIdx.x * 64;
    const int l0 = blockIdx.y * 64;
    const int t  = threadIdx.x;
    const int cl = (t & 15) * 4;
    #pragma unroll
    for (int i = 0; i < 4; ++i) {
        int row = (t >> 4) + i * 16;
        size_t gi = ((size_t)b * SEQ + n0 + row) * 256 + l0 + cl;
        float4 xv = *(const float4*)(x + gi);
        u16x4 xb = { f2bf(xv.x), f2bf(xv.y), f2bf(xv.z), f2bf(xv.w) };
        *(u16x4*)(x_bf + gi) = xb;
        xs[row][cl+0] = xv.x; xs[row][cl+1] = xv.y;
        xs[row][cl+2] = xv.z; xs[row][cl+3] = xv.w;
    }
    __syncthreads();
    const int lrow = t >> 2;
    const int nseg = (t & 3) * 16;
    size_t obase = ((size_t)b * 256 + l0 + lrow) * 1024 + n0 + nseg;
    #pragma unroll
    for (int h = 0; h < 2; ++h) {
        u16x8 v;
        #pragma unroll
        for (int j = 0; j < 8; ++j) v[j] = f2bf(xs[nseg + h * 8 + j][lrow]);
        *(u16x8*)(xT + obase + h * 8) = v;
    }
}

// =====================================================================
// prep_w: wsum = bf16(w1+w2) [256][1024], w1g = bf16(g*w1) [256][1024],
//         dww = bf16(dw_w)   [1024][1024]
// =====================================================================
__global__ __launch_bounds__(256)
void prep_w(const float* __restrict__ fc_w, const float* __restrict__ dw_w,
            const float* __restrict__ gamma,
            unsigned short* __restrict__ wsum, unsigned short* __restrict__ w1g,
            unsigned short* __restrict__ dww)
{
    int idx = blockIdx.x * 256 + threadIdx.x;   // float4 index
    if (idx < 65536) {                           // 256*1024/4
        float g = gamma[0];
        int o = idx >> 8, q = (idx & 255) * 4;
        float4 w1 = *(const float4*)(fc_w + (size_t)o * 2048 + q);
        float4 w2 = *(const float4*)(fc_w + (size_t)o * 2048 + 1024 + q);
        u16x4 s  = { f2bf(w1.x + w2.x), f2bf(w1.y + w2.y),
                     f2bf(w1.z + w2.z), f2bf(w1.w + w2.w) };
        u16x4 gq = { f2bf(g * w1.x), f2bf(g * w1.y), f2bf(g * w1.z), f2bf(g * w1.w) };
        *(u16x4*)(wsum + (size_t)idx * 4) = s;
        *(u16x4*)(w1g  + (size_t)idx * 4) = gq;
    } else {
        int j = idx - 65536;                     // 1024*1024/4 quads
        float4 v = *(const float4*)(dw_w + (size_t)j * 4);
        u16x4 o2 = { f2bf(v.x), f2bf(v.y), f2bf(v.z), f2bf(v.w) };
        *(u16x4*)(dww + (size_t)j * 4) = o2;
    }
}

// =====================================================================
// MFMA NT GEMM, 128x128 tile, BK=64, double-buffered LDS, counted vmcnt,
// XOR-swizzled LDS (bank-conflict-free), chunked XCD blockIdx swizzle.
//   EPI 0: sigmoid(acc+bias[col]) -> bf16   (adjT; + optional (A2,B2) pass)
//   EPI 1: leaky(acc)             -> bf16   (y1T)
//   EPI 2: leaky(acc+bias[row])   -> f32    (out)
// =====================================================================
template<int EPI, bool OPT2>
__global__ __launch_bounds__(256)
void gemm_nt(const unsigned short* __restrict__ A, long sA, int lda,
             const unsigned short* __restrict__ B, long sB, int ldb,
             const unsigned short* __restrict__ A2, int lda2,
             const unsigned short* __restrict__ B2, int ldb2,
             const float* __restrict__ gamma,
             void* __restrict__ Cv, long sC, int ldc,
             const float* __restrict__ bias, int K)
{
    __shared__ char smem[65536];       // 2 bufs x (A 16K + B 16K)
    const int nwg = gridDim.x * gridDim.y * gridDim.z;
    int flat = blockIdx.x + gridDim.x * (blockIdx.y + gridDim.y * blockIdx.z);
    flat = xcd_swz(flat, nwg);
    const int bx = flat % gridDim.x;
    const int rem = flat / gridDim.x;
    const int by = rem % gridDim.y;
    const int bz = rem / gridDim.y;
    const int m0 = by * 128, n0 = bx * 128;
    const int t = threadIdx.x, w = t >> 6, lane = t & 63;
    const int wm0 = (w >> 1) * 64, wn0 = (w & 1) * 64;
    f32x4 acc[4][4] = {};

    float g = 0.0f;
    if (OPT2) {
        g = gamma[0];
        asm volatile("s_waitcnt vmcnt(0)" ::: "memory");  // keep vmcnt counting clean
    }

    auto stage = [&](const unsigned short* Ag, int ldA,
                     const unsigned short* Bg, int ldB, int k0, int buf) {
        char* As = smem + buf * 32768;
        char* Bs = As + 16384;
        #pragma unroll
        for (int i = 0; i < 4; ++i) {
            int chunk = i * 4 + w;                 // wave-uniform 1KB LDS chunk
            int off = chunk * 1024 + lane * 16;
            int r = off >> 7;                      // tile row (128B = 64 bf16)
            int c = ((off >> 4) & 7) ^ (r & 7);    // pre-swizzled source 16B chunk
            gload_lds16(Ag + (size_t)(m0 + r) * ldA + k0 + c * 8, As + chunk * 1024);
            gload_lds16(Bg + (size_t)(n0 + r) * ldB + k0 + c * 8, Bs + chunk * 1024);
        }
    };

    auto compute = [&](int buf) {
        char* As = smem + buf * 32768;
        char* Bs = As + 16384;
        s16x8 af[4][2], bfr[4][2];
        #pragma unroll
        for (int mi = 0; mi < 4; ++mi)
            #pragma unroll
            for (int kk = 0; kk < 2; ++kk) {
                int ra = wm0 + mi * 16 + (lane & 15);
                int bca = (kk * 64 + ((lane >> 4) * 16)) ^ ((ra & 7) << 4);
                af[mi][kk] = *(const s16x8*)(As + ra * 128 + bca);
                int rb = wn0 + mi * 16 + (lane & 15);
                int bcb = (kk * 64 + ((lane >> 4) * 16)) ^ ((rb & 7) << 4);
                bfr[mi][kk] = *(const s16x8*)(Bs + rb * 128 + bcb);
            }
        #pragma unroll
        for (int mi = 0; mi < 4; ++mi)
            #pragma unroll
            for (int ni = 0; ni < 4; ++ni) {
                acc[mi][ni] = __builtin_amdgcn_mfma_f32_16x16x32_bf16(af[mi][0], bfr[ni][0], acc[mi][ni], 0, 0, 0);
                acc[mi][ni] = __builtin_amdgcn_mfma_f32_16x16x32_bf16(af[mi][1], bfr[ni][1], acc[mi][ni], 0, 0, 0);
            }
    };

    auto run = [&](const unsigned short* Ag, int ldA,
                   const unsigned short* Bg, int ldB, int Kl) {
        const int NT = Kl >> 6;
        stage(Ag, ldA, Bg, ldB, 0, 0);             // prologue: 8 loads in flight
        for (int tt = 0; tt < NT; ++tt) {
            int cur = tt & 1;
            if (tt + 1 < NT) {
                stage(Ag, ldA, Bg, ldB, (tt + 1) << 6, cur ^ 1);  // 16 in flight
                asm volatile("s_waitcnt vmcnt(8)" ::: "memory");  // oldest 8 (cur) landed
            } else {
                asm volatile("s_waitcnt vmcnt(0)" ::: "memory");
            }
            __builtin_amdgcn_s_barrier();          // all waves: cur fully staged
            __builtin_amdgcn_sched_barrier(0);
            compute(cur);
            __builtin_amdgcn_sched_barrier(0);
            __builtin_amdgcn_s_barrier();          // all waves done reading cur
        }
    };

    run(A + (size_t)bz * sA, lda, B + (size_t)bz * sB, ldb, K);
    if (OPT2) {
        if (g != 0.0f) run(A2, lda2, B2, ldb2, K);   // uniform; hot path skips
    }

    #pragma unroll
    for (int mi = 0; mi < 4; ++mi) {
        int row0 = m0 + wm0 + mi * 16 + ((lane >> 4) << 2);
        #pragma unroll
        for (int ni = 0; ni < 4; ++ni) {
            int col = n0 + wn0 + ni * 16 + (lane & 15);
            float bcol = (EPI == 0) ? bias[col] : 0.0f;
            #pragma unroll
            for (int j = 0; j < 4; ++j) {
                float v = acc[mi][ni][j];
                if (EPI == 0) {
                    v = 1.0f / (1.0f + __expf(-(v + bcol)));
                    ((unsigned short*)Cv)[(size_t)bz * sC + (size_t)(row0 + j) * ldc + col] = f2bf(v);
                } else if (EPI == 1) {
                    v = leaky(v);
                    ((unsigned short*)Cv)[(size_t)bz * sC + (size_t)(row0 + j) * ldc + col] = f2bf(v);
                } else {
                    v = leaky(v + bias[row0 + j]);
                    ((float*)Cv)[(size_t)bz * sC + (size_t)(row0 + j) * ldc + col] = v;
                }
            }
        }
    }
}

// =====================================================================
extern "C" void kernel_launch(void* const* d_in, const int* in_sizes, int n_in,
                              void* d_out, int out_size, void* d_ws, size_t ws_size,
                              hipStream_t stream)
{
    (void)in_sizes; (void)n_in; (void)out_size; (void)ws_size;
    const float* x     = (const float*)d_in[0];
    const float* qkv_w = (const float*)d_in[1];
    const float* qkv_b = (const float*)d_in[2];
    const float* gamma = (const float*)d_in[3];
    const float* fc_w  = (const float*)d_in[4];
    const float* fc_b  = (const float*)d_in[5];
    const float* dw_w  = (const float*)d_in[6];
    const float* dw_b  = (const float*)d_in[7];
    float* out = (float*)d_out;

    char* ws = (char*)d_ws;
    unsigned short* xT   = (unsigned short*)(ws);              // 33,554,432 B
    unsigned short* x_bf = (unsigned short*)(ws + 33554432);   // 33,554,432 B
    unsigned short* adjT = (unsigned short*)(ws + 67108864);   //  8,388,608 B
    unsigned short* y1T  = (unsigned short*)(ws + 75497472);   // 33,554,432 B
    unsigned short* wsum = (unsigned short*)(ws + 109051904);  //    524,288 B
    unsigned short* w1g  = (unsigned short*)(ws + 109576192);  //    524,288 B
    unsigned short* dwwb = (unsigned short*)(ws + 110100480);  //  2,097,152 B
    float*          O    = (float*)        (ws + 112197632);   // 67,108,864 B (cold)
    unsigned short* OT   = (unsigned short*)(ws + 179306496);  // 33,554,432 B (cold)
    __hip_bfloat16* qkv  = (__hip_bfloat16*)(ws);              // cold; aliases hot bufs (dead before conv_xT)

    // Cold path (persistent small grids; no-op dispatches when gamma == 0).
    qkv_gemm   <<<512,  256, 0, stream>>>(x, qkv_w, qkv_b, gamma, qkv);
    attn_kernel<<<1024, 256, 0, stream>>>(qkv, gamma, O);
    conv_OT    <<<512,  256, 0, stream>>>(O, gamma, OT);

    // Hot prep.
    prep_w <<<1280, 256, 0, stream>>>(fc_w, dw_w, gamma, wsum, w1g, dwwb);
    conv_xT<<<dim3(16, 4, NB), 256, 0, stream>>>(x, xT, x_bf);

    // adjT[(b,l)][o] = sigmoid( xT.wsum^T [+ OT.(g*w1)^T] + fc_b[o] )  M=16384 N=256 K=1024
    gemm_nt<0, true><<<dim3(2, 128, 1), 256, 0, stream>>>(
        xT, 0L, 1024, wsum, 0L, 1024, OT, 1024, w1g, 1024, gamma,
        adjT, 0L, 256, fc_b, 1024);
    // y1T[b][l][n] = leaky( adjT[b] . x_bf[b]^T )                      M=256 N=1024 K=256
    gemm_nt<1, false><<<dim3(8, 2, NB), 256, 0, stream>>>(
        adjT, 65536L, 256, x_bf, 262144L, 256, nullptr, 0, nullptr, 0, gamma,
        y1T, 262144L, 1024, nullptr, 256);
    // out[b][o][l] = leaky( dw_w . y1T[b]^T + dw_b[o] )                M=1024 N=256 K=1024
    gemm_nt<2, false><<<dim3(2, 8, NB), 256, 0, stream>>>(
        dwwb, 0L, 1024, y1T, 262144L, 1024, nullptr, 0, nullptr, 0, gamma,
        out, 262144L, 256, dw_b, 1024);
}

// Round 5
// 215.618 us; speedup vs baseline: 4.1407x; 1.0471x over previous
//
#include <hip/hip_runtime.h>
#include <hip/hip_bf16.h>

#define NEG_SLOPE 0.2f

static constexpr int NB  = 64;
static constexpr int SEQ = 1024;

typedef __attribute__((ext_vector_type(8))) short  s16x8;
typedef __attribute__((ext_vector_type(4))) float  f32x4;
typedef __attribute__((ext_vector_type(8))) unsigned short u16x8;
typedef __attribute__((ext_vector_type(4))) unsigned short u16x4;

typedef __attribute__((address_space(1))) void gvoid;
typedef __attribute__((address_space(3))) void lvoid;

__device__ __forceinline__ float bf2f(unsigned short u) {
    return __uint_as_float(((unsigned int)u) << 16);
}
__device__ __forceinline__ unsigned short f2bf(float f) {
    __hip_bfloat16 h = __float2bfloat16(f);
    return *reinterpret_cast<unsigned short*>(&h);
}
__device__ __forceinline__ float leaky(float v) {
    return v >= 0.0f ? v : NEG_SLOPE * v;
}
__device__ __forceinline__ void gload_lds16(const void* g, void* l) {
    __builtin_amdgcn_global_load_lds((const gvoid*)(size_t)g,
                                     (lvoid*)(unsigned int)(size_t)l, 16, 0, 0);
}

// =====================================================================
// Cold path (gamma != 0 only) — persistent grid-stride kernels; when
// gamma==0 each is a tiny no-op dispatch (96 blocks load gamma + exit).
// =====================================================================
__global__ __launch_bounds__(256)
void qkv_gemm(const float* __restrict__ x, const float* __restrict__ w,
              const float* __restrict__ bias, const float* __restrict__ gamma,
              __hip_bfloat16* __restrict__ qkv)
{
    if (gamma[0] == 0.0f) return;
    __shared__ float As[16][68];
    __shared__ float Bs[16][68];
    const int t  = threadIdx.x;
    const int tx = t & 15, ty = t >> 4;
    for (int u = blockIdx.x; u < 12 * 1024; u += gridDim.x) {
        const int n0 = (u % 12) * 64;
        const int m0 = (u / 12) * 64;
        float acc[4][4] = {};
        for (int k0 = 0; k0 < 256; k0 += 16) {
            #pragma unroll
            for (int i = 0; i < 4; ++i) {
                int idx = t + i * 256;
                int mm = idx >> 4, kk = idx & 15;
                As[kk][mm] = x[(size_t)(m0 + mm) * 256 + k0 + kk];
                Bs[kk][mm] = w[(size_t)(n0 + mm) * 256 + k0 + kk];
            }
            __syncthreads();
            #pragma unroll
            for (int kk = 0; kk < 16; ++kk) {
                float4 av = *(const float4*)&As[kk][ty * 4];
                float4 bv = *(const float4*)&Bs[kk][tx * 4];
                float a[4] = {av.x, av.y, av.z, av.w};
                float bb[4] = {bv.x, bv.y, bv.z, bv.w};
                #pragma unroll
                for (int i = 0; i < 4; ++i)
                    #pragma unroll
                    for (int j = 0; j < 4; ++j)
                        acc[i][j] += a[i] * bb[j];
            }
            __syncthreads();
        }
        #pragma unroll
        for (int i = 0; i < 4; ++i) {
            int m = m0 + ty * 4 + i;
            #pragma unroll
            for (int j = 0; j < 4; ++j) {
                int e = n0 + tx * 4 + j;
                qkv[(size_t)m * 768 + e] = __float2bfloat16(acc[i][j] + bias[e]);
            }
        }
        __syncthreads();
    }
}

__global__ __launch_bounds__(256)
void attn_kernel(const __hip_bfloat16* __restrict__ qkvh,
                 const float* __restrict__ gamma, float* __restrict__ O)
{
    if (gamma[0] == 0.0f) return;
    const unsigned short* qkv = (const unsigned short*)qkvh;
    const int lane = threadIdx.x & 63;
    for (int u = blockIdx.x; u < NB * 256; u += gridDim.x) {
        const int b = u >> 8;
        const int n = (u & 255) * 4 + (threadIdx.x >> 6);
        const size_t base = (size_t)b * SEQ * 768;
        const unsigned short* qp = qkv + base + (size_t)n * 768 + lane * 4;
        float q0 = bf2f(qp[0]), q1 = bf2f(qp[1]), q2 = bf2f(qp[2]), q3 = bf2f(qp[3]);
        float m = -INFINITY, l = 0.f, a0 = 0.f, a1 = 0.f, a2 = 0.f, a3 = 0.f;
        for (int j = 0; j < SEQ; ++j) {
            const unsigned short* kp = qkv + base + (size_t)j * 768 + 256 + lane * 4;
            float s = q0 * bf2f(kp[0]) + q1 * bf2f(kp[1]) + q2 * bf2f(kp[2]) + q3 * bf2f(kp[3]);
            #pragma unroll
            for (int off = 32; off; off >>= 1) s += __shfl_xor(s, off);
            float mn = fmaxf(m, s);
            float corr = __expf(m - mn);
            float p = __expf(s - mn);
            l = l * corr + p;
            const unsigned short* vp = qkv + base + (size_t)j * 768 + 512 + lane * 4;
            a0 = a0 * corr + p * bf2f(vp[0]);
            a1 = a1 * corr + p * bf2f(vp[1]);
            a2 = a2 * corr + p * bf2f(vp[2]);
            a3 = a3 * corr + p * bf2f(vp[3]);
            m = mn;
        }
        float inv = 1.f / l;
        float* op = O + ((size_t)b * SEQ + n) * 256 + lane * 4;
        op[0] = a0 * inv; op[1] = a1 * inv; op[2] = a2 * inv; op[3] = a3 * inv;
    }
}

// Cold: OT[b][l][n] = bf16( O[b][n][l] )   (flat [16384][1024])
__global__ __launch_bounds__(256)
void conv_OT(const float* __restrict__ O, const float* __restrict__ gamma,
             unsigned short* __restrict__ OT)
{
    if (gamma[0] == 0.0f) return;
    __shared__ float xs[64][68];
    const int t  = threadIdx.x;
    const int cl = (t & 15) * 4;
    for (int u = blockIdx.x; u < 16 * 4 * NB; u += gridDim.x) {
        const int n0 = (u & 15) * 64;
        const int l0 = ((u >> 4) & 3) * 64;
        const int b  = u >> 6;
        #pragma unroll
        for (int i = 0; i < 4; ++i) {
            int row = (t >> 4) + i * 16;
            size_t gi = ((size_t)b * SEQ + n0 + row) * 256 + l0 + cl;
            float4 xv = *(const float4*)(O + gi);
            xs[row][cl+0] = xv.x; xs[row][cl+1] = xv.y;
            xs[row][cl+2] = xv.z; xs[row][cl+3] = xv.w;
        }
        __syncthreads();
        const int lrow = t >> 2;
        const int nseg = (t & 3) * 16;
        size_t obase = ((size_t)b * 256 + l0 + lrow) * 1024 + n0 + nseg;
        #pragma unroll
        for (int h = 0; h < 2; ++h) {
            u16x8 v;
            #pragma unroll
            for (int j = 0; j < 8; ++j) v[j] = f2bf(xs[nseg + h * 8 + j][lrow]);
            *(u16x8*)(OT + obase + h * 8) = v;
        }
        __syncthreads();
    }
}

// =====================================================================
// prep_conv (fused hot prep):
//   jobs [0, 4096):  xT[b][l][n] = bf16(x[b][n][l]) (flat [16384][1024]) and
//                    x_bf = bf16(x) (straight copy), 64x64 tile per job
//   jobs [4096, 5376): wsum = bf16(w1+w2), w1g = bf16(g*w1), dww = bf16(dw_w)
// Branch is block-uniform; barriers only inside the conv branch.
// =====================================================================
__global__ __launch_bounds__(256)
void prep_conv(const float* __restrict__ x, const float* __restrict__ fc_w,
               const float* __restrict__ dw_w, const float* __restrict__ gamma,
               unsigned short* __restrict__ xT, unsigned short* __restrict__ x_bf,
               unsigned short* __restrict__ wsum, unsigned short* __restrict__ w1g,
               unsigned short* __restrict__ dww)
{
    __shared__ float xs[64][68];
    const int t = threadIdx.x;
    const int u = blockIdx.x;
    if (u < 4096) {
        const int b  = u >> 6;
        const int n0 = (u & 15) * 64;
        const int l0 = ((u >> 4) & 3) * 64;
        const int cl = (t & 15) * 4;
        #pragma unroll
        for (int i = 0; i < 4; ++i) {
            int row = (t >> 4) + i * 16;
            size_t gi = ((size_t)b * SEQ + n0 + row) * 256 + l0 + cl;
            float4 xv = *(const float4*)(x + gi);
            u16x4 xb = { f2bf(xv.x), f2bf(xv.y), f2bf(xv.z), f2bf(xv.w) };
            *(u16x4*)(x_bf + gi) = xb;
            xs[row][cl+0] = xv.x; xs[row][cl+1] = xv.y;
            xs[row][cl+2] = xv.z; xs[row][cl+3] = xv.w;
        }
        __syncthreads();
        const int lrow = t >> 2;
        const int nseg = (t & 3) * 16;
        size_t obase = ((size_t)b * 256 + l0 + lrow) * 1024 + n0 + nseg;
        #pragma unroll
        for (int h = 0; h < 2; ++h) {
            u16x8 v;
            #pragma unroll
            for (int j = 0; j < 8; ++j) v[j] = f2bf(xs[nseg + h * 8 + j][lrow]);
            *(u16x8*)(xT + obase + h * 8) = v;
        }
    } else {
        int idx = (u - 4096) * 256 + t;          // float4 index
        if (idx < 65536) {                        // 256*1024/4
            float g = gamma[0];
            int o = idx >> 8, q = (idx & 255) * 4;
            float4 w1 = *(const float4*)(fc_w + (size_t)o * 2048 + q);
            float4 w2 = *(const float4*)(fc_w + (size_t)o * 2048 + 1024 + q);
            u16x4 s  = { f2bf(w1.x + w2.x), f2bf(w1.y + w2.y),
                         f2bf(w1.z + w2.z), f2bf(w1.w + w2.w) };
            u16x4 gq = { f2bf(g * w1.x), f2bf(g * w1.y), f2bf(g * w1.z), f2bf(g * w1.w) };
            *(u16x4*)(wsum + (size_t)idx * 4) = s;
            *(u16x4*)(w1g  + (size_t)idx * 4) = gq;
        } else {
            int j = idx - 65536;                  // 1024*1024/4 quads
            float4 v = *(const float4*)(dw_w + (size_t)j * 4);
            u16x4 o2 = { f2bf(v.x), f2bf(v.y), f2bf(v.z), f2bf(v.w) };
            *(u16x4*)(dww + (size_t)j * 4) = o2;
        }
    }
}

// =====================================================================
// MFMA NT GEMM, 128x128 tile, BK=64, double-buffered LDS, counted vmcnt,
// XOR-swizzled LDS (bank-conflict-free). No XCD swizzle (r4 A/B: it cost
// 24% on the dw gemm by thrashing per-XCD L2 while HBM was not binding).
//   EPI 0: sigmoid(acc+bias[col]) -> bf16   (adjT; + optional (A2,B2) pass)
//   EPI 1: leaky(acc)             -> bf16   (y1T)
//   EPI 2: leaky(acc+bias[row])   -> f32    (out)
// =====================================================================
template<int EPI, bool OPT2>
__global__ __launch_bounds__(256)
void gemm_nt(const unsigned short* __restrict__ A, long sA, int lda,
             const unsigned short* __restrict__ B, long sB, int ldb,
             const unsigned short* __restrict__ A2, int lda2,
             const unsigned short* __restrict__ B2, int ldb2,
             const float* __restrict__ gamma,
             void* __restrict__ Cv, long sC, int ldc,
             const float* __restrict__ bias, int K)
{
    __shared__ char smem[65536];       // 2 bufs x (A 16K + B 16K)
    const int bz = blockIdx.z;
    const int m0 = blockIdx.y * 128, n0 = blockIdx.x * 128;
    const int t = threadIdx.x, w = t >> 6, lane = t & 63;
    const int wm0 = (w >> 1) * 64, wn0 = (w & 1) * 64;
    f32x4 acc[4][4] = {};

    float g = 0.0f;
    if (OPT2) {
        g = gamma[0];
        asm volatile("s_waitcnt vmcnt(0)" ::: "memory");  // keep vmcnt counting clean
    }

    auto stage = [&](const unsigned short* Ag, int ldA,
                     const unsigned short* Bg, int ldB, int k0, int buf) {
        char* As = smem + buf * 32768;
        char* Bs = As + 16384;
        #pragma unroll
        for (int i = 0; i < 4; ++i) {
            int chunk = i * 4 + w;                 // wave-uniform 1KB LDS chunk
            int off = chunk * 1024 + lane * 16;
            int r = off >> 7;                      // tile row (128B = 64 bf16)
            int c = ((off >> 4) & 7) ^ (r & 7);    // pre-swizzled source 16B chunk
            gload_lds16(Ag + (size_t)(m0 + r) * ldA + k0 + c * 8, As + chunk * 1024);
            gload_lds16(Bg + (size_t)(n0 + r) * ldB + k0 + c * 8, Bs + chunk * 1024);
        }
    };

    auto compute = [&](int buf) {
        char* As = smem + buf * 32768;
        char* Bs = As + 16384;
        s16x8 af[4][2], bfr[4][2];
        #pragma unroll
        for (int mi = 0; mi < 4; ++mi)
            #pragma unroll
            for (int kk = 0; kk < 2; ++kk) {
                int ra = wm0 + mi * 16 + (lane & 15);
                int bca = (kk * 64 + ((lane >> 4) * 16)) ^ ((ra & 7) << 4);
                af[mi][kk] = *(const s16x8*)(As + ra * 128 + bca);
                int rb = wn0 + mi * 16 + (lane & 15);
                int bcb = (kk * 64 + ((lane >> 4) * 16)) ^ ((rb & 7) << 4);
                bfr[mi][kk] = *(const s16x8*)(Bs + rb * 128 + bcb);
            }
        #pragma unroll
        for (int mi = 0; mi < 4; ++mi)
            #pragma unroll
            for (int ni = 0; ni < 4; ++ni) {
                acc[mi][ni] = __builtin_amdgcn_mfma_f32_16x16x32_bf16(af[mi][0], bfr[ni][0], acc[mi][ni], 0, 0, 0);
                acc[mi][ni] = __builtin_amdgcn_mfma_f32_16x16x32_bf16(af[mi][1], bfr[ni][1], acc[mi][ni], 0, 0, 0);
            }
    };

    auto run = [&](const unsigned short* Ag, int ldA,
                   const unsigned short* Bg, int ldB, int Kl) {
        const int NT = Kl >> 6;
        stage(Ag, ldA, Bg, ldB, 0, 0);             // prologue: 8 loads in flight
        for (int tt = 0; tt < NT; ++tt) {
            int cur = tt & 1;
            if (tt + 1 < NT) {
                stage(Ag, ldA, Bg, ldB, (tt + 1) << 6, cur ^ 1);  // 16 in flight
                asm volatile("s_waitcnt vmcnt(8)" ::: "memory");  // oldest 8 (cur) landed
            } else {
                asm volatile("s_waitcnt vmcnt(0)" ::: "memory");
            }
            __builtin_amdgcn_s_barrier();          // all waves: cur fully staged
            __builtin_amdgcn_sched_barrier(0);
            compute(cur);
            __builtin_amdgcn_sched_barrier(0);
            __builtin_amdgcn_s_barrier();          // all waves done reading cur
        }
    };

    run(A + (size_t)bz * sA, lda, B + (size_t)bz * sB, ldb, K);
    if (OPT2) {
        if (g != 0.0f) run(A2, lda2, B2, ldb2, K);   // uniform; hot path skips
    }

    #pragma unroll
    for (int mi = 0; mi < 4; ++mi) {
        int row0 = m0 + wm0 + mi * 16 + ((lane >> 4) << 2);
        #pragma unroll
        for (int ni = 0; ni < 4; ++ni) {
            int col = n0 + wn0 + ni * 16 + (lane & 15);
            float bcol = (EPI == 0) ? bias[col] : 0.0f;
            #pragma unroll
            for (int j = 0; j < 4; ++j) {
                float v = acc[mi][ni][j];
                if (EPI == 0) {
                    v = 1.0f / (1.0f + __expf(-(v + bcol)));
                    ((unsigned short*)Cv)[(size_t)bz * sC + (size_t)(row0 + j) * ldc + col] = f2bf(v);
                } else if (EPI == 1) {
                    v = leaky(v);
                    ((unsigned short*)Cv)[(size_t)bz * sC + (size_t)(row0 + j) * ldc + col] = f2bf(v);
                } else {
                    v = leaky(v + bias[row0 + j]);
                    ((float*)Cv)[(size_t)bz * sC + (size_t)(row0 + j) * ldc + col] = v;
                }
            }
        }
    }
}

// =====================================================================
extern "C" void kernel_launch(void* const* d_in, const int* in_sizes, int n_in,
                              void* d_out, int out_size, void* d_ws, size_t ws_size,
                              hipStream_t stream)
{
    (void)in_sizes; (void)n_in; (void)out_size; (void)ws_size;
    const float* x     = (const float*)d_in[0];
    const float* qkv_w = (const float*)d_in[1];
    const float* qkv_b = (const float*)d_in[2];
    const float* gamma = (const float*)d_in[3];
    const float* fc_w  = (const float*)d_in[4];
    const float* fc_b  = (const float*)d_in[5];
    const float* dw_w  = (const float*)d_in[6];
    const float* dw_b  = (const float*)d_in[7];
    float* out = (float*)d_out;

    char* ws = (char*)d_ws;
    unsigned short* xT   = (unsigned short*)(ws);              // 33,554,432 B
    unsigned short* x_bf = (unsigned short*)(ws + 33554432);   // 33,554,432 B
    unsigned short* adjT = (unsigned short*)(ws + 67108864);   //  8,388,608 B
    unsigned short* y1T  = (unsigned short*)(ws + 75497472);   // 33,554,432 B
    unsigned short* wsum = (unsigned short*)(ws + 109051904);  //    524,288 B
    unsigned short* w1g  = (unsigned short*)(ws + 109576192);  //    524,288 B
    unsigned short* dwwb = (unsigned short*)(ws + 110100480);  //  2,097,152 B
    float*          O    = (float*)        (ws + 112197632);   // 67,108,864 B (cold)
    unsigned short* OT   = (unsigned short*)(ws + 179306496);  // 33,554,432 B (cold)
    __hip_bfloat16* qkv  = (__hip_bfloat16*)(ws);              // cold; aliases hot bufs (dead before prep_conv)

    // Cold path (tiny no-op dispatches when gamma == 0).
    qkv_gemm   <<<96, 256, 0, stream>>>(x, qkv_w, qkv_b, gamma, qkv);
    attn_kernel<<<96, 256, 0, stream>>>(qkv, gamma, O);
    conv_OT    <<<96, 256, 0, stream>>>(O, gamma, OT);

    // Hot prep (fused transpose/cast + weight prep).
    prep_conv<<<5376, 256, 0, stream>>>(x, fc_w, dw_w, gamma, xT, x_bf, wsum, w1g, dwwb);

    // adjT[(b,l)][o] = sigmoid( xT.wsum^T [+ OT.(g*w1)^T] + fc_b[o] )  M=16384 N=256 K=1024
    gemm_nt<0, true><<<dim3(2, 128, 1), 256, 0, stream>>>(
        xT, 0L, 1024, wsum, 0L, 1024, OT, 1024, w1g, 1024, gamma,
        adjT, 0L, 256, fc_b, 1024);
    // y1T[b][l][n] = leaky( adjT[b] . x_bf[b]^T )                      M=256 N=1024 K=256
    gemm_nt<1, false><<<dim3(8, 2, NB), 256, 0, stream>>>(
        adjT, 65536L, 256, x_bf, 262144L, 256, nullptr, 0, nullptr, 0, gamma,
        y1T, 262144L, 1024, nullptr, 256);
    // out[b][o][l] = leaky( dw_w . y1T[b]^T + dw_b[o] )                M=1024 N=256 K=1024
    gemm_nt<2, false><<<dim3(2, 8, NB), 256, 0, stream>>>(
        dwwb, 0L, 1024, y1T, 262144L, 1024, nullptr, 0, nullptr, 0, gamma,
        out, 262144L, 256, dw_b, 1024);
}